// Round 16
// baseline (4449.490 us; speedup 1.0000x reference)
//
#include <hip/hip_runtime.h>
#include <hip/hip_bf16.h>

#define QD 1024
#define AD 26
#define BD 128
#define LD 1024
#define NWG 64           // 32 q-slices (M=32) x 2; 4 waves/WG = 8 batch-groups
#define PSTR (8 * 32 * 512)      // ushorts per parity of packed alpha (256 KB)

typedef short bf16x8 __attribute__((ext_vector_type(8)));
typedef float f32x4 __attribute__((ext_vector_type(4)));

static __device__ __forceinline__ unsigned short f2bf(float f) {
    __hip_bfloat16 h = __float2bfloat16(f);
    return *reinterpret_cast<unsigned short*>(&h);
}

// Agent-scope relaxed 16B load (two 8B atomic loads -> served at device coherence pt).
static __device__ __forceinline__ bf16x8 load_a16(const unsigned short* p) {
    unsigned long long lo = __hip_atomic_load((const unsigned long long*)p,
                                              __ATOMIC_RELAXED, __HIP_MEMORY_SCOPE_AGENT);
    unsigned long long hi = __hip_atomic_load((const unsigned long long*)(p + 4),
                                              __ATOMIC_RELAXED, __HIP_MEMORY_SCOPE_AGENT);
    union { unsigned long long q[2]; bf16x8 v; } u;
    u.q[0] = lo; u.q[1] = hi;
    return u.v;
}

// Agent-scope relaxed 8B store (fire-and-forget; atomic => no tearing of a granule).
static __device__ __forceinline__ void store_a8(unsigned short* p, unsigned long long q) {
    __hip_atomic_store((unsigned long long*)p, q,
                       __ATOMIC_RELAXED, __HIP_MEMORY_SCOPE_AGENT);
}

// Row-softmax of trans_logits [1024,1024] -> bf16 packed as A-fragments of T^T.
// A-frag layout (16x16x32): A[m = lane&15][k = quad*8 + j].
__global__ void softmax_pack_T(const float* __restrict__ tl, unsigned short* __restrict__ tf) {
    const int i = blockIdx.x;      // q_in
    const int tid = threadIdx.x;   // 256
    __shared__ float red[256];
    float v[4];
    float m = -1e30f;
    for (int c = 0; c < 4; ++c) { v[c] = tl[i * QD + tid + 256 * c]; m = fmaxf(m, v[c]); }
    red[tid] = m; __syncthreads();
    for (int s = 128; s > 0; s >>= 1) { if (tid < s) red[tid] = fmaxf(red[tid], red[tid + s]); __syncthreads(); }
    m = red[0]; __syncthreads();
    float sum = 0.f;
    for (int c = 0; c < 4; ++c) { v[c] = expf(v[c] - m); sum += v[c]; }
    red[tid] = sum; __syncthreads();
    for (int s = 128; s > 0; s >>= 1) { if (tid < s) red[tid] += red[tid + s]; __syncthreads(); }
    const float inv = 1.0f / red[0];
    const int kt = i >> 5, quad = (i >> 3) & 3, j = i & 7;
    for (int c = 0; c < 4; ++c) {
        const int q = tid + 256 * c;
        const int mt = q >> 4, col = q & 15;
        tf[(size_t)((mt * 32 + kt) * 64 + quad * 16 + col) * 8 + j] = f2bf(v[c] * inv);
    }
}

// Row-softmax of emis_logits [1024,26] -> bf16 A-fragments (M=q, K=a padded to 32).
__global__ void softmax_pack_B(const float* __restrict__ el, unsigned short* __restrict__ bmf) {
    const int q = blockIdx.x * blockDim.x + threadIdx.x;
    if (q >= QD) return;
    float v[AD];
    float m = -1e30f;
    for (int a = 0; a < AD; ++a) { v[a] = el[q * AD + a]; m = fmaxf(m, v[a]); }
    float sum = 0.f;
    for (int a = 0; a < AD; ++a) { v[a] = expf(v[a] - m); sum += v[a]; }
    const float inv = 1.0f / sum;
    const int mt = q >> 4, col = q & 15;
    for (int a = 0; a < 32; ++a) {
        const float val = (a < AD) ? v[a] * inv : 0.f;
        bmf[(size_t)(mt * 64 + (a >> 3) * 16 + col) * 8 + (a & 7)] = f2bf(val);
    }
}

__global__ void softmax_pi(const float* __restrict__ il, float* __restrict__ pi) {
    const int tid = threadIdx.x;   // 1024
    __shared__ float red[1024];
    const float v = il[tid];
    red[tid] = v; __syncthreads();
    for (int s = 512; s > 0; s >>= 1) { if (tid < s) red[tid] = fmaxf(red[tid], red[tid + s]); __syncthreads(); }
    const float m = red[0]; __syncthreads();
    const float e = expf(v - m);
    red[tid] = e; __syncthreads();
    for (int s = 512; s > 0; s >>= 1) { if (tid < s) red[tid] += red[tid + s]; __syncthreads(); }
    pi[tid] = e / red[0];
}

// Scan: 64 WGs x 256 threads = 256 independent waves; PLAIN launch (cooperative API's
// silent rejection was the R9/R10/R12/R14 zero-output mode). Wave (qp = blockIdx>>1,
// grp = (blockIdx&1)*4 + wave) owns a 32q x 16b tile: M=32 halves the consumer count
// per batch-group (32 waves instead of 64 read each group's alpha -> scoped-sweep
// volume 16 MB/step -> 8 MB/step) and one validated chunk feeds 3 MFMAs.
// Self-validating exchange (proven R15): alpha >= 0, sign bits are phase tags
// ((t>>1)&1 on elements 2,3 of each 8-B granule). The consumer's load sweep IS the
// poll: validate sign patterns, retry while stale, strip, MFMA. A slot holds t,
// t-2 (opposite phase), or 0xAA fill (invalid for both). Anti-overrun: storing t+1
// requires having fully validated t, which implies all readers of t-1 finished.
// Producer wave's C-tile maps to consumer B-frag chunk kt=qp directly:
// granule (mt, quad, col) -> lane_c = (mt*2 + (quad>>1))*16 + col, j0 = (quad&1)*4.
__launch_bounds__(256, 1)
__global__ void hmm_scan(const float* __restrict__ inputs,
                         const unsigned short* __restrict__ tf,
                         const unsigned short* __restrict__ bmf,
                         const float* __restrict__ pi,
                         unsigned short* __restrict__ apack,  // 2 x PSTR ushorts (0xAA)
                         float* __restrict__ out) {
    const int tid   = threadIdx.x;
    const int wave  = tid >> 6;
    const int lane  = tid & 63;
    const int quad  = lane >> 4;
    const int col   = lane & 15;
    const int qp    = (int)blockIdx.x >> 1;           // q-slice 0..31 (M=32)
    const int grp   = ((int)blockIdx.x & 1) * 4 + wave;  // batch group 0..7
    const int b     = grp * 16 + col;                 // this lane's batch

    // Producer store targets (ushort offsets within a parity): m-tile mt at +mt*256.
    const size_t poff = (size_t)((grp * 32 + qp) * 64 + (quad >> 1) * 16 + col) * 8
                      + (quad & 1) * 4;
    // Consumer chunk base; chunk kt at +kt*512.
    const size_t coff = (size_t)(grp * 32) * 512 + (size_t)lane * 8;

    // 64 T^T A-frags (two 16-q m-tiles x 32 chunks) into the unified register file.
    bf16x8 tfr0[32], tfr1[32];
    {
        const bf16x8* t0 = (const bf16x8*)tf + (size_t)(qp * 2) * 32 * 64 + lane;
        const bf16x8* t1 = (const bf16x8*)tf + (size_t)(qp * 2 + 1) * 32 * 64 + lane;
        #pragma unroll
        for (int kt = 0; kt < 32; ++kt) {
            tfr0[kt] = t0[(size_t)kt * 64];
            tfr1[kt] = t1[(size_t)kt * 64];
        }
    }
    const bf16x8 bmA0 = *(const bf16x8*)&bmf[(size_t)((qp * 2) * 64 + lane) * 8];
    const bf16x8 bmA1 = *(const bf16x8*)&bmf[(size_t)((qp * 2 + 1) * 64 + lane) * 8];
    float pr0[4], pr1[4];
    #pragma unroll
    for (int r = 0; r < 4; ++r) {
        pr0[r] = pi[qp * 32 + quad * 4 + r];
        pr1[r] = pi[qp * 32 + 16 + quad * 4 + r];
    }

    bf16x8 ones;
    #pragma unroll
    for (int i = 0; i < 8; ++i) ones[i] = (short)0x3F80;

    const f32x4 fz = {0.f, 0.f, 0.f, 0.f};
    const unsigned M = 0x80008000u;
    float ll = 0.f;

    // Emission(0): direct register loads (shared x-fragment, two A-frags).
    f32x4 e0, e1;
    {
        bf16x8 xb;
        #pragma unroll
        for (int j = 0; j < 8; ++j) {
            const int a = quad * 8 + j;
            const float v = (a < AD) ? inputs[(size_t)b * LD * AD + a] : 0.f;
            xb[j] = (short)f2bf(v);
        }
        e0 = __builtin_amdgcn_mfma_f32_16x16x32_bf16(bmA0, xb, fz, 0, 0, 0);
        e1 = __builtin_amdgcn_mfma_f32_16x16x32_bf16(bmA1, xb, fz, 0, 0, 0);
    }

    f32x4 acc0 = fz, acc1 = fz, on = fz;

    for (int t = 0; t < LD; ++t) {
        float v0[4], v1[4];
        if (t == 0) {
            #pragma unroll
            for (int r = 0; r < 4; ++r) { v0[r] = pr0[r] * e0[r]; v1[r] = pr1[r] * e1[r]; }
        } else {
            const float i0 = 1.f / on[0];
            #pragma unroll
            for (int r = 0; r < 4; ++r) {
                v0[r] = acc0[r] * e0[r] * i0;
                v1[r] = acc1[r] * e1[r] * i0;
            }
        }
        // Tag elements 2,3 of each granule with phase(t); fire-and-forget stores.
        const unsigned long long tag =
            ((t >> 1) & 1) ? 0x8000800000000000ULL : 0ULL;
        unsigned long long uq0 =
              (unsigned long long)f2bf(v0[0])
            | ((unsigned long long)f2bf(v0[1]) << 16)
            | ((unsigned long long)f2bf(v0[2]) << 32)
            | ((unsigned long long)f2bf(v0[3]) << 48);
        unsigned long long uq1 =
              (unsigned long long)f2bf(v1[0])
            | ((unsigned long long)f2bf(v1[1]) << 16)
            | ((unsigned long long)f2bf(v1[2]) << 32)
            | ((unsigned long long)f2bf(v1[3]) << 48);
        unsigned short* pw = apack + (size_t)(t & 1) * PSTR + poff;
        store_a8(pw, uq0 | tag);
        store_a8(pw + 256, uq1 | tag);

        if (qp == 0 && t > 0) ll += logf(on[0]);   // on[0] == c_{t-1}[lane's batch]

        if (t + 1 < LD) {
            // Emission(t+1) while our stores are in flight.
            bf16x8 xb;
            #pragma unroll
            for (int j = 0; j < 8; ++j) {
                const int a = quad * 8 + j;
                const float v = (a < AD)
                    ? inputs[((size_t)b * LD + (t + 1)) * AD + a] : 0.f;
                xb[j] = (short)f2bf(v);
            }
            e0 = __builtin_amdgcn_mfma_f32_16x16x32_bf16(bmA0, xb, fz, 0, 0, 0);
            e1 = __builtin_amdgcn_mfma_f32_16x16x32_bf16(bmA1, xb, fz, 0, 0, 0);

            // Validating consume of alpha(t), two halves of 16 chunks each.
            const unsigned short* cp = apack + (size_t)(t & 1) * PSTR + coff;
            const unsigned E = ((t >> 1) & 1) ? M : 0u;
            acc0 = fz; acc1 = fz; on = fz;
            #pragma unroll
            for (int h = 0; h < 2; ++h) {
                bf16x8 bufr[16];
                unsigned bad;
                do {
                    #pragma unroll
                    for (int k = 0; k < 16; ++k)
                        bufr[k] = load_a16(cp + (size_t)(h * 16 + k) * 512);
                    bad = 0u;
                    #pragma unroll
                    for (int k = 0; k < 16; ++k) {
                        union { bf16x8 v; uint4 u; } w; w.v = bufr[k];
                        bad |= (w.u.x | w.u.z | (w.u.y ^ E) | (w.u.w ^ E)) & M;
                    }
                } while (__ballot(bad == 0u) != ~0ULL);
                #pragma unroll
                for (int k = 0; k < 16; ++k) {
                    union { bf16x8 v; uint4 u; } w; w.v = bufr[k];
                    w.u.x &= ~M; w.u.y &= ~M; w.u.z &= ~M; w.u.w &= ~M;
                    acc0 = __builtin_amdgcn_mfma_f32_16x16x32_bf16(tfr0[h * 16 + k], w.v, acc0, 0, 0, 0);
                    acc1 = __builtin_amdgcn_mfma_f32_16x16x32_bf16(tfr1[h * 16 + k], w.v, acc1, 0, 0, 0);
                    on   = __builtin_amdgcn_mfma_f32_16x16x32_bf16(ones, w.v, on, 0, 0, 0);
                }
            }
        }
    }

    // Final normalizer c_{L-1}; only qp==0 waves produce output.
    if (qp == 0) {
        const unsigned short* cp = apack + (size_t)((LD - 1) & 1) * PSTR + coff;
        const unsigned E = (((LD - 1) >> 1) & 1) ? M : 0u;
        f32x4 f0 = fz;
        #pragma unroll
        for (int h = 0; h < 2; ++h) {
            bf16x8 bufr[16];
            unsigned bad;
            do {
                #pragma unroll
                for (int k = 0; k < 16; ++k)
                    bufr[k] = load_a16(cp + (size_t)(h * 16 + k) * 512);
                bad = 0u;
                #pragma unroll
                for (int k = 0; k < 16; ++k) {
                    union { bf16x8 v; uint4 u; } w; w.v = bufr[k];
                    bad |= (w.u.x | w.u.z | (w.u.y ^ E) | (w.u.w ^ E)) & M;
                }
            } while (__ballot(bad == 0u) != ~0ULL);
            #pragma unroll
            for (int k = 0; k < 16; ++k) {
                union { bf16x8 v; uint4 u; } w; w.v = bufr[k];
                w.u.x &= ~M; w.u.y &= ~M; w.u.z &= ~M; w.u.w &= ~M;
                f0 = __builtin_amdgcn_mfma_f32_16x16x32_bf16(ones, w.v, f0, 0, 0, 0);
            }
        }
        if (quad == 0) out[b] = ll + logf(f0[0]);
    }
}

extern "C" void kernel_launch(void* const* d_in, const int* in_sizes, int n_in,
                              void* d_out, int out_size, void* d_ws, size_t ws_size,
                              hipStream_t stream) {
    const float* inputs       = (const float*)d_in[0];
    const float* init_logits  = (const float*)d_in[1];
    const float* trans_logits = (const float*)d_in[2];
    const float* emis_logits  = (const float*)d_in[3];
    float* out = (float*)d_out;

    unsigned short* tf    = (unsigned short*)d_ws;                 // 2 MB
    unsigned short* bmf   = tf + (size_t)QD * QD;                  // 64 KB
    float* pi             = (float*)(bmf + (size_t)QD * 32);       // 4 KB
    unsigned short* apack = (unsigned short*)(pi + QD);            // 512 KB

    // Self-contained tag init: 0xAA bytes => every bf16 sign bit set => invalid
    // for BOTH phases.
    hipMemsetAsync(apack, 0xAA, (size_t)2 * PSTR * sizeof(unsigned short), stream);

    softmax_pack_T<<<1024, 256, 0, stream>>>(trans_logits, tf);
    softmax_pack_B<<<4, 256, 0, stream>>>(emis_logits, bmf);
    softmax_pi<<<1, 1024, 0, stream>>>(init_logits, pi);

    // Plain launch: 64 blocks trivially co-resident; no cooperative API.
    hmm_scan<<<NWG, 256, 0, stream>>>(inputs, tf, bmf, pi, apack, out);
}

// Round 17
// 4405.397 us; speedup vs baseline: 1.0100x; 1.0100x over previous
//
#include <hip/hip_runtime.h>
#include <hip/hip_bf16.h>

#define QD 1024
#define AD 26
#define BD 128
#define LD 1024
#define NWG 64           // 32 q-slices (M=32/wave) x 2 blocks; 4 waves = 8 batch-groups
#define PSTR (8 * 32 * 512)      // ushorts per parity of packed alpha (256 KB)

typedef short bf16x8 __attribute__((ext_vector_type(8)));
typedef float f32x4 __attribute__((ext_vector_type(4)));

static __device__ __forceinline__ unsigned short f2bf(float f) {
    __hip_bfloat16 h = __float2bfloat16(f);
    return *reinterpret_cast<unsigned short*>(&h);
}

// Agent-scope relaxed 16B load (two 8B atomic loads -> served at device coherence pt).
static __device__ __forceinline__ bf16x8 load_a16(const unsigned short* p) {
    unsigned long long lo = __hip_atomic_load((const unsigned long long*)p,
                                              __ATOMIC_RELAXED, __HIP_MEMORY_SCOPE_AGENT);
    unsigned long long hi = __hip_atomic_load((const unsigned long long*)(p + 4),
                                              __ATOMIC_RELAXED, __HIP_MEMORY_SCOPE_AGENT);
    union { unsigned long long q[2]; bf16x8 v; } u;
    u.q[0] = lo; u.q[1] = hi;
    return u.v;
}

// Agent-scope relaxed 8B store (fire-and-forget; atomic => no tearing of a granule).
static __device__ __forceinline__ void store_a8(unsigned short* p, unsigned long long q) {
    __hip_atomic_store((unsigned long long*)p, q,
                       __ATOMIC_RELAXED, __HIP_MEMORY_SCOPE_AGENT);
}

// Row-softmax of trans_logits [1024,1024] -> bf16 packed as A-fragments of T^T.
// A-frag layout (16x16x32): A[m = lane&15][k = quad*8 + j].
__global__ void softmax_pack_T(const float* __restrict__ tl, unsigned short* __restrict__ tf) {
    const int i = blockIdx.x;      // q_in
    const int tid = threadIdx.x;   // 256
    __shared__ float red[256];
    float v[4];
    float m = -1e30f;
    for (int c = 0; c < 4; ++c) { v[c] = tl[i * QD + tid + 256 * c]; m = fmaxf(m, v[c]); }
    red[tid] = m; __syncthreads();
    for (int s = 128; s > 0; s >>= 1) { if (tid < s) red[tid] = fmaxf(red[tid], red[tid + s]); __syncthreads(); }
    m = red[0]; __syncthreads();
    float sum = 0.f;
    for (int c = 0; c < 4; ++c) { v[c] = expf(v[c] - m); sum += v[c]; }
    red[tid] = sum; __syncthreads();
    for (int s = 128; s > 0; s >>= 1) { if (tid < s) red[tid] += red[tid + s]; __syncthreads(); }
    const float inv = 1.0f / red[0];
    const int kt = i >> 5, quad = (i >> 3) & 3, j = i & 7;
    for (int c = 0; c < 4; ++c) {
        const int q = tid + 256 * c;
        const int mt = q >> 4, col = q & 15;
        tf[(size_t)((mt * 32 + kt) * 64 + quad * 16 + col) * 8 + j] = f2bf(v[c] * inv);
    }
}

// Row-softmax of emis_logits [1024,26] -> bf16 A-fragments (M=q, K=a padded to 32).
__global__ void softmax_pack_B(const float* __restrict__ el, unsigned short* __restrict__ bmf) {
    const int q = blockIdx.x * blockDim.x + threadIdx.x;
    if (q >= QD) return;
    float v[AD];
    float m = -1e30f;
    for (int a = 0; a < AD; ++a) { v[a] = el[q * AD + a]; m = fmaxf(m, v[a]); }
    float sum = 0.f;
    for (int a = 0; a < AD; ++a) { v[a] = expf(v[a] - m); sum += v[a]; }
    const float inv = 1.0f / sum;
    const int mt = q >> 4, col = q & 15;
    for (int a = 0; a < 32; ++a) {
        const float val = (a < AD) ? v[a] * inv : 0.f;
        bmf[(size_t)(mt * 64 + (a >> 3) * 16 + col) * 8 + (a & 7)] = f2bf(val);
    }
}

__global__ void softmax_pi(const float* __restrict__ il, float* __restrict__ pi) {
    const int tid = threadIdx.x;   // 1024
    __shared__ float red[1024];
    const float v = il[tid];
    red[tid] = v; __syncthreads();
    for (int s = 512; s > 0; s >>= 1) { if (tid < s) red[tid] = fmaxf(red[tid], red[tid + s]); __syncthreads(); }
    const float m = red[0]; __syncthreads();
    const float e = expf(v - m);
    red[tid] = e; __syncthreads();
    for (int s = 512; s > 0; s >>= 1) { if (tid < s) red[tid] += red[tid + s]; __syncthreads(); }
    pi[tid] = e / red[0];
}

// Scan: 64 WGs x 256 threads = 256 independent waves, PLAIN launch. Wave
// (qp = blockIdx>>1, grp = (blockIdx&1)*4 + wave) owns a 32q x 16b tile. M=32
// halves the scoped-sweep volume vs R15 (32 consumer waves per batch-group, not
// 64) and one validated chunk feeds 3 MFMAs (acc0, acc1, shared ones-chain).
// R16's register-spill regression is fixed by putting the WG-shared 64 T A-frags
// in LDS (all 4 waves share qp): 64 KB loaded once, 2 ds_read_b128 per chunk.
// Live registers: bufr[16] + accumulators (~R15 envelope). Self-validating
// exchange (proven R15/R16): alpha >= 0, sign bits are phase tags ((t>>1)&1 on
// elements 2,3 of each granule); load sweep IS the poll; a slot holds t, t-2
// (opposite phase), or 0xAA fill (invalid for both). Anti-overrun: storing t+1
// requires fully validated t => all readers of t-1 finished.
__launch_bounds__(256, 1)
__global__ void hmm_scan(const float* __restrict__ inputs,
                         const unsigned short* __restrict__ tf,
                         const unsigned short* __restrict__ bmf,
                         const float* __restrict__ pi,
                         unsigned short* __restrict__ apack,  // 2 x PSTR ushorts (0xAA)
                         float* __restrict__ out) {
    __shared__ unsigned short ts[2 * 32 * 64 * 8];   // 64 KB: both m-tiles' T A-frags

    const int tid   = threadIdx.x;
    const int wave  = tid >> 6;
    const int lane  = tid & 63;
    const int quad  = lane >> 4;
    const int col   = lane & 15;
    const int qp    = (int)blockIdx.x >> 1;              // q-slice 0..31 (M=32)
    const int grp   = ((int)blockIdx.x & 1) * 4 + wave;  // batch group 0..7
    const int b     = grp * 16 + col;                    // this lane's batch

    // Producer store targets (ushort offsets within a parity): m-tile mt at +mt*256.
    const size_t poff = (size_t)((grp * 32 + qp) * 64 + (quad >> 1) * 16 + col) * 8
                      + (quad & 1) * 4;
    // Consumer chunk base; chunk kt at +kt*512.
    const size_t coff = (size_t)(grp * 32) * 512 + (size_t)lane * 8;

    // WG-shared T slice (both m-tiles, contiguous 64 KB) into LDS once.
    {
        const float4* src = (const float4*)(tf + (size_t)(qp * 2) * 32 * 64 * 8);
        float4* dst = (float4*)ts;
        for (int i = tid; i < 4096; i += 256) dst[i] = src[i];
    }
    const bf16x8 bmA0 = *(const bf16x8*)&bmf[(size_t)((qp * 2) * 64 + lane) * 8];
    const bf16x8 bmA1 = *(const bf16x8*)&bmf[(size_t)((qp * 2 + 1) * 64 + lane) * 8];
    float pr0[4], pr1[4];
    #pragma unroll
    for (int r = 0; r < 4; ++r) {
        pr0[r] = pi[qp * 32 + quad * 4 + r];
        pr1[r] = pi[qp * 32 + 16 + quad * 4 + r];
    }

    bf16x8 ones;
    #pragma unroll
    for (int i = 0; i < 8; ++i) ones[i] = (short)0x3F80;

    const f32x4 fz = {0.f, 0.f, 0.f, 0.f};
    const unsigned M = 0x80008000u;
    float ll = 0.f;
    __syncthreads();   // ts ready (only barrier; loop itself is wave-independent)

    // Emission(0): direct register loads (shared x-fragment, two A-frags).
    f32x4 e0, e1;
    {
        bf16x8 xb;
        #pragma unroll
        for (int j = 0; j < 8; ++j) {
            const int a = quad * 8 + j;
            const float v = (a < AD) ? inputs[(size_t)b * LD * AD + a] : 0.f;
            xb[j] = (short)f2bf(v);
        }
        e0 = __builtin_amdgcn_mfma_f32_16x16x32_bf16(bmA0, xb, fz, 0, 0, 0);
        e1 = __builtin_amdgcn_mfma_f32_16x16x32_bf16(bmA1, xb, fz, 0, 0, 0);
    }

    f32x4 acc0 = fz, acc1 = fz, on = fz;

    for (int t = 0; t < LD; ++t) {
        float v0[4], v1[4];
        if (t == 0) {
            #pragma unroll
            for (int r = 0; r < 4; ++r) { v0[r] = pr0[r] * e0[r]; v1[r] = pr1[r] * e1[r]; }
        } else {
            const float i0 = 1.f / on[0];
            #pragma unroll
            for (int r = 0; r < 4; ++r) {
                v0[r] = acc0[r] * e0[r] * i0;
                v1[r] = acc1[r] * e1[r] * i0;
            }
        }
        // Tag elements 2,3 of each granule with phase(t); fire-and-forget stores.
        const unsigned long long tag =
            ((t >> 1) & 1) ? 0x8000800000000000ULL : 0ULL;
        unsigned long long uq0 =
              (unsigned long long)f2bf(v0[0])
            | ((unsigned long long)f2bf(v0[1]) << 16)
            | ((unsigned long long)f2bf(v0[2]) << 32)
            | ((unsigned long long)f2bf(v0[3]) << 48);
        unsigned long long uq1 =
              (unsigned long long)f2bf(v1[0])
            | ((unsigned long long)f2bf(v1[1]) << 16)
            | ((unsigned long long)f2bf(v1[2]) << 32)
            | ((unsigned long long)f2bf(v1[3]) << 48);
        unsigned short* pw = apack + (size_t)(t & 1) * PSTR + poff;
        store_a8(pw, uq0 | tag);
        store_a8(pw + 256, uq1 | tag);

        if (qp == 0 && t > 0) ll += logf(on[0]);   // on[0] == c_{t-1}[lane's batch]

        if (t + 1 < LD) {
            // Emission(t+1) while our stores are in flight.
            bf16x8 xb;
            #pragma unroll
            for (int j = 0; j < 8; ++j) {
                const int a = quad * 8 + j;
                const float v = (a < AD)
                    ? inputs[((size_t)b * LD + (t + 1)) * AD + a] : 0.f;
                xb[j] = (short)f2bf(v);
            }
            e0 = __builtin_amdgcn_mfma_f32_16x16x32_bf16(bmA0, xb, fz, 0, 0, 0);
            e1 = __builtin_amdgcn_mfma_f32_16x16x32_bf16(bmA1, xb, fz, 0, 0, 0);

            // Validating consume of alpha(t), two halves of 16 chunks each.
            const unsigned short* cp = apack + (size_t)(t & 1) * PSTR + coff;
            const unsigned E = ((t >> 1) & 1) ? M : 0u;
            acc0 = fz; acc1 = fz; on = fz;
            #pragma unroll
            for (int h = 0; h < 2; ++h) {
                bf16x8 bufr[16];
                unsigned bad;
                do {
                    #pragma unroll
                    for (int k = 0; k < 16; ++k)
                        bufr[k] = load_a16(cp + (size_t)(h * 16 + k) * 512);
                    bad = 0u;
                    #pragma unroll
                    for (int k = 0; k < 16; ++k) {
                        union { bf16x8 v; uint4 u; } w; w.v = bufr[k];
                        bad |= (w.u.x | w.u.z | (w.u.y ^ E) | (w.u.w ^ E)) & M;
                    }
                } while (__ballot(bad == 0u) != ~0ULL);
                #pragma unroll
                for (int k = 0; k < 16; ++k) {
                    union { bf16x8 v; uint4 u; } w; w.v = bufr[k];
                    w.u.x &= ~M; w.u.y &= ~M; w.u.z &= ~M; w.u.w &= ~M;
                    const int kt = h * 16 + k;
                    bf16x8 af0 = *(const bf16x8*)&ts[(size_t)(kt * 64 + lane) * 8];
                    bf16x8 af1 = *(const bf16x8*)&ts[(size_t)((32 + kt) * 64 + lane) * 8];
                    acc0 = __builtin_amdgcn_mfma_f32_16x16x32_bf16(af0, w.v, acc0, 0, 0, 0);
                    acc1 = __builtin_amdgcn_mfma_f32_16x16x32_bf16(af1, w.v, acc1, 0, 0, 0);
                    on   = __builtin_amdgcn_mfma_f32_16x16x32_bf16(ones, w.v, on, 0, 0, 0);
                }
            }
        }
    }

    // Final normalizer c_{L-1}; only qp==0 waves produce output.
    if (qp == 0) {
        const unsigned short* cp = apack + (size_t)((LD - 1) & 1) * PSTR + coff;
        const unsigned E = (((LD - 1) >> 1) & 1) ? M : 0u;
        f32x4 f0 = fz;
        #pragma unroll
        for (int h = 0; h < 2; ++h) {
            bf16x8 bufr[16];
            unsigned bad;
            do {
                #pragma unroll
                for (int k = 0; k < 16; ++k)
                    bufr[k] = load_a16(cp + (size_t)(h * 16 + k) * 512);
                bad = 0u;
                #pragma unroll
                for (int k = 0; k < 16; ++k) {
                    union { bf16x8 v; uint4 u; } w; w.v = bufr[k];
                    bad |= (w.u.x | w.u.z | (w.u.y ^ E) | (w.u.w ^ E)) & M;
                }
            } while (__ballot(bad == 0u) != ~0ULL);
            #pragma unroll
            for (int k = 0; k < 16; ++k) {
                union { bf16x8 v; uint4 u; } w; w.v = bufr[k];
                w.u.x &= ~M; w.u.y &= ~M; w.u.z &= ~M; w.u.w &= ~M;
                f0 = __builtin_amdgcn_mfma_f32_16x16x32_bf16(ones, w.v, f0, 0, 0, 0);
            }
        }
        if (quad == 0) out[b] = ll + logf(f0[0]);
    }
}

extern "C" void kernel_launch(void* const* d_in, const int* in_sizes, int n_in,
                              void* d_out, int out_size, void* d_ws, size_t ws_size,
                              hipStream_t stream) {
    const float* inputs       = (const float*)d_in[0];
    const float* init_logits  = (const float*)d_in[1];
    const float* trans_logits = (const float*)d_in[2];
    const float* emis_logits  = (const float*)d_in[3];
    float* out = (float*)d_out;

    unsigned short* tf    = (unsigned short*)d_ws;                 // 2 MB
    unsigned short* bmf   = tf + (size_t)QD * QD;                  // 64 KB
    float* pi             = (float*)(bmf + (size_t)QD * 32);       // 4 KB
    unsigned short* apack = (unsigned short*)(pi + QD);            // 512 KB

    // Self-contained tag init: 0xAA bytes => every bf16 sign bit set => invalid
    // for BOTH phases.
    hipMemsetAsync(apack, 0xAA, (size_t)2 * PSTR * sizeof(unsigned short), stream);

    softmax_pack_T<<<1024, 256, 0, stream>>>(trans_logits, tf);
    softmax_pack_B<<<4, 256, 0, stream>>>(emis_logits, bmf);
    softmax_pi<<<1, 1024, 0, stream>>>(init_logits, pi);

    // Plain launch: 64 blocks trivially co-resident; no cooperative API.
    hmm_scan<<<NWG, 256, 0, stream>>>(inputs, tf, bmf, pi, apack, out);
}